// Round 9
// baseline (111.259 us; speedup 1.0000x reference)
//
#include <hip/hip_runtime.h>

constexpr int Bc = 4, Nc = 16384, Mc = 4096, Kc = 32;
constexpr float EPSc = 1e-5f;
constexpr float L2E = 1.4426950408889634f;   // log2(e)

using bf16x8 = __attribute__((ext_vector_type(8))) short;   // 8 bf16 (4 VGPRs)
using f32x4  = __attribute__((ext_vector_type(4))) float;   // 4 fp32

__device__ inline unsigned f2bf_bits(float x) {
    unsigned u = __float_as_uint(x);
    return (u + 0x7fffu + ((u >> 16) & 1u)) >> 16;
}
__device__ inline short f2bf(float x) { return (short)f2bf_bits(x); }

// ---------------------------------------------------------------------------
// pt_enc (MFMA): Sfa[n][c] = pack( hi = bf16((f_bn + dot(x_n,w_c))*log2e),
//                                  lo = bf16(a_bn + dot(x_n,w_c)) )
// REPS>1 = diagnostic repeat mode (opaque pointers, ws scratch output).
// ---------------------------------------------------------------------------
template<int REPS>
__global__ __launch_bounds__(256) void pt_enc(
    const float* __restrict__ feats, const float* __restrict__ xyz,
    const float* __restrict__ Wf, const float* __restrict__ Wa,
    const float* __restrict__ Wx,
    const float* __restrict__ fg, const float* __restrict__ fb,
    const float* __restrict__ fm, const float* __restrict__ fv,
    const float* __restrict__ ag, const float* __restrict__ ab,
    const float* __restrict__ am, const float* __restrict__ av,
    const float* __restrict__ xg, const float* __restrict__ xb,
    const float* __restrict__ xm, const float* __restrict__ xv,
    unsigned* __restrict__ Sfa)
{
    __shared__ __align__(16) short WT[128][72];   // [col][k]
    __shared__ unsigned stile[4][16][68];         // transpose tile per wave
    __shared__ float  sx[64][3];                  // block's 64 points' xyz
    __shared__ float4 scw[64];                    // per-channel {w0,w1,w2,-}
    __shared__ float  bis[128];

    const int tid = threadIdx.x, lane = tid & 63, w = tid >> 6;
    const int row16 = lane & 15, kg = lane >> 4;
    const long long row0 = (long long)blockIdx.x * 64;

    if (tid < 192) ((float*)sx)[tid] = xyz[row0 * 3 + tid];
    if (tid < 64) {
        const float xs = xg[tid] * rsqrtf(xv[tid] + EPSc);
        scw[tid] = make_float4(Wx[tid] * xs, Wx[64 + tid] * xs,
                               Wx[128 + tid] * xs, 0.f);
    }
    if (tid < 128) {
        const int c = tid & 63;
        const float g  = (tid < 64) ? fg[c] : ag[c];
        const float v  = (tid < 64) ? fv[c] : av[c];
        const float bb = (tid < 64) ? fb[c] : ab[c];
        const float mm = (tid < 64) ? fm[c] : am[c];
        const float s = g * rsqrtf(v + EPSc);
        bis[tid] = (tid < 64) ? (bb - mm * s) * L2E : (bb - mm * s);
    }
    {   // WT staging: thread owns channel c = tid&63 for both planes
        const int c = tid & 63, k0 = tid >> 6;
        const float sf = fg[c] * rsqrtf(fv[c] + EPSc) * L2E;
        const float sa = ag[c] * rsqrtf(av[c] + EPSc);
#pragma unroll
        for (int it = 0; it < 16; ++it) {
            const int k = k0 + 4 * it;
            WT[c][k]      = f2bf(Wf[k * 64 + c] * sf);
            WT[64 + c][k] = f2bf(Wa[k * 64 + c] * sa);
        }
    }
    __syncthreads();

    for (int rep = 0; rep < REPS; ++rep) {
        const float* fp = feats; unsigned* op = Sfa;
        if constexpr (REPS > 1) asm volatile("" : "+s"(fp), "+s"(op));

        bf16x8 bfr[8][2];
#pragma unroll
        for (int t = 0; t < 8; ++t)
#pragma unroll
            for (int h = 0; h < 2; ++h)
                bfr[t][h] = *(const bf16x8*)&WT[16 * t + row16][32 * h + kg * 8];

        const long long base = row0 + w * 16;
        const float* arow = fp + (base + row16) * 64 + kg * 8;
        const float4 v0 = *(const float4*)(arow + 0);
        const float4 v1 = *(const float4*)(arow + 4);
        const float4 v2 = *(const float4*)(arow + 32);
        const float4 v3 = *(const float4*)(arow + 36);
        bf16x8 af0, af1;
        af0[0]=f2bf(v0.x); af0[1]=f2bf(v0.y); af0[2]=f2bf(v0.z); af0[3]=f2bf(v0.w);
        af0[4]=f2bf(v1.x); af0[5]=f2bf(v1.y); af0[6]=f2bf(v1.z); af0[7]=f2bf(v1.w);
        af1[0]=f2bf(v2.x); af1[1]=f2bf(v2.y); af1[2]=f2bf(v2.z); af1[3]=f2bf(v2.w);
        af1[4]=f2bf(v3.x); af1[5]=f2bf(v3.y); af1[6]=f2bf(v3.z); af1[7]=f2bf(v3.w);

        f32x4 acc[8];
#pragma unroll
        for (int t = 0; t < 8; ++t) {
            f32x4 z = {0.f, 0.f, 0.f, 0.f};
            z = __builtin_amdgcn_mfma_f32_16x16x32_bf16(af0, bfr[t][0], z, 0, 0, 0);
            z = __builtin_amdgcn_mfma_f32_16x16x32_bf16(af1, bfr[t][1], z, 0, 0, 0);
            acc[t] = z;
        }

        float4 cwt[4];
#pragma unroll
        for (int t = 0; t < 4; ++t)
            cwt[t] = scw[16 * t + row16];

        if constexpr (REPS > 1) __syncthreads();   // protect stile across reps

        const int lrow = w * 16 + kg * 4;
        // C/D layout: row=(lane>>4)*4+reg, col=lane&15 -> LDS tile -> coalesced
#pragma unroll
        for (int r = 0; r < 4; ++r) {
            const float x0 = sx[lrow + r][0], x1 = sx[lrow + r][1], x2 = sx[lrow + r][2];
#pragma unroll
            for (int t = 0; t < 4; ++t) {
                const int c = 16 * t + row16;
                const float px = fmaf(x0, cwt[t].x, fmaf(x1, cwt[t].y, x2 * cwt[t].z));
                stile[w][kg * 4 + r][c] =
                      f2bf_bits(acc[t + 4][r] + bis[64 + c] + px)
                    | (f2bf_bits(acc[t][r] + bis[c] + px * L2E) << 16);
            }
        }
        __syncthreads();
#pragma unroll
        for (int rr = 0; rr < 16; ++rr)
            op[(base + rr) * 64 + lane] = stile[w][rr][lane];
    }
}

// ---------------------------------------------------------------------------
// pt_gr5: 512 thr = 8 waves, 2 groups/wave (16/block), 1024 blocks.
// readlane -> SGPR index -> SALU gather addressing. REPS>1 = diagnostic mode.
// ---------------------------------------------------------------------------
template<int REPS>
__global__ __launch_bounds__(512) void pt_gr5(
    const float* __restrict__ nxyz, const unsigned* __restrict__ Sfa,
    const float* __restrict__ Wr,
    const float* __restrict__ rg, const float* __restrict__ rb,
    const float* __restrict__ rm, const float* __restrict__ rv,
    const float* __restrict__ Wx,
    const float* __restrict__ xg, const float* __restrict__ xb,
    const float* __restrict__ xm, const float* __restrict__ xv,
    const int* __restrict__ gidx, const int* __restrict__ gcnt,
    float* __restrict__ out)
{
    __shared__ __align__(16) short WT[128][72];   // refine weights [col][k]
    __shared__ __align__(16) short snf[16][72];   // softmax outputs [group][ch]

    const int tid = threadIdx.x, lane = tid & 63, w = tid >> 6;
    const int row16 = lane & 15, kg = lane >> 4;
    // bijective XCD-pinning swizzle: xcd = blk%8 serves batch (blk%8)>>1
    const int i = blockIdx.x;                     // 0..1023
    const int b = (i & 7) >> 1;
    const int j = ((i >> 3) << 1) | (i & 1);      // 0..255
    const long long gbase = (long long)b * Mc + j * 16;

    {   // WT staging: thread owns channel c = tid&127 (scale in registers)
        const int c = tid & 127, k0 = tid >> 7;
        const float sr = rg[c] * rsqrtf(rv[c] + EPSc);
#pragma unroll
        for (int it = 0; it < 16; ++it) {
            const int k = k0 + 4 * it;
            WT[c][k] = f2bf(Wr[k * 128 + c] * sr);
        }
    }
    if constexpr (REPS > 1) __syncthreads();

    // per-lane channel coeffs (channel = lane)
    const float xs = xg[lane] * rsqrtf(xv[lane] + EPSc);
    const float w0 = Wx[lane] * xs, w1 = Wx[64 + lane] * xs, w2 = Wx[128 + lane] * xs;
    const float P = xb[lane] - xm[lane] * xs;

    for (int rep = 0; rep < REPS; ++rep) {
        const unsigned* sfp = Sfa; const int* gip = gidx; float* op = out;
        if constexpr (REPS > 1) asm volatile("" : "+s"(sfp), "+s"(gip), "+s"(op));

        // both groups' neighbor lists in one coalesced 64-int load (wave-local)
        const int nv = gip[(gbase + 2 * w) * 32 + lane];

        const float* nx = nxyz + (gbase + 2 * w) * 3;  // 6 floats = both groups
        const float QA = P - fmaf(nx[0], w0, fmaf(nx[1], w1, nx[2] * w2));
        const float QB = P - fmaf(nx[3], w0, fmaf(nx[4], w1, nx[5] * w2));
        const float QlA = QA * L2E, QlB = QB * L2E;

        const unsigned* sbase = sfp + (long long)b * (Nc * 64) + lane;
        float ssA = 0.f, acA = 0.f, ssB = 0.f, acB = 0.f;
#pragma unroll
        for (int k = 0; k < Kc; ++k) {
            const int nA = __builtin_amdgcn_readlane(nv, k);        // SGPR index
            const int nB = __builtin_amdgcn_readlane(nv, 32 + k);
            const unsigned dA = sbase[nA << 6];    // SALU-addressed 256B gather
            const unsigned dB = sbase[nB << 6];
            const float eA = __builtin_amdgcn_exp2f(__uint_as_float(dA & 0xffff0000u) + QlA);
            const float aA = __uint_as_float(dA << 16) + QA;
            const float eB = __builtin_amdgcn_exp2f(__uint_as_float(dB & 0xffff0000u) + QlB);
            const float aB = __uint_as_float(dB << 16) + QB;
            ssA += eA; acA = fmaf(eA, aA, acA);
            ssB += eB; acB = fmaf(eB, aB, acB);
        }
        snf[2 * w][lane]     = f2bf(acA * __builtin_amdgcn_rcpf(ssA));
        snf[2 * w + 1][lane] = f2bf(acB * __builtin_amdgcn_rcpf(ssB));
        __syncthreads();

        // refine MFMA: A = snf (16 rows), B = WT col-tile w
        const bf16x8 af0 = *(const bf16x8*)&snf[row16][kg * 8];
        const bf16x8 af1 = *(const bf16x8*)&snf[row16][32 + kg * 8];
        const bf16x8 bf0 = *(const bf16x8*)&WT[16 * w + row16][kg * 8];
        const bf16x8 bf1 = *(const bf16x8*)&WT[16 * w + row16][32 + kg * 8];
        f32x4 z = {0.f, 0.f, 0.f, 0.f};
        z = __builtin_amdgcn_mfma_f32_16x16x32_bf16(af0, bf0, z, 0, 0, 0);
        z = __builtin_amdgcn_mfma_f32_16x16x32_bf16(af1, bf1, z, 0, 0, 0);

        // epilogue: BN+ReLU+mask
        const int4 c4 = *(const int4*)(gcnt + gbase + kg * 4);
        const int cc = 16 * w + row16;
        const float sr = rg[cc] * rsqrtf(rv[cc] + EPSc);
        const float bb = rb[cc] - rm[cc] * sr;
        float* orow = op + (gbase + kg * 4) * 128 + cc;
        __builtin_nontemporal_store(fmaxf(z[0] + bb, 0.f) * (c4.x > 0 ? 1.f : 0.f), orow);
        __builtin_nontemporal_store(fmaxf(z[1] + bb, 0.f) * (c4.y > 0 ? 1.f : 0.f), orow + 128);
        __builtin_nontemporal_store(fmaxf(z[2] + bb, 0.f) * (c4.z > 0 ? 1.f : 0.f), orow + 256);
        __builtin_nontemporal_store(fmaxf(z[3] + bb, 0.f) * (c4.w > 0 ? 1.f : 0.f), orow + 384);
        if constexpr (REPS > 1) __syncthreads();   // protect snf across reps
    }
}

extern "C" void kernel_launch(void* const* d_in, const int* in_sizes, int n_in,
                              void* d_out, int out_size, void* d_ws, size_t ws_size,
                              hipStream_t stream)
{
    const float* xyz  = (const float*)d_in[0];
    const float* nxyz = (const float*)d_in[1];
    const float* feats = (const float*)d_in[2];
    const float* Wf = (const float*)d_in[3];
    const float* fg = (const float*)d_in[4];
    const float* fb = (const float*)d_in[5];
    const float* fm = (const float*)d_in[6];
    const float* fv = (const float*)d_in[7];
    const float* Wa = (const float*)d_in[8];
    const float* ag = (const float*)d_in[9];
    const float* ab = (const float*)d_in[10];
    const float* am = (const float*)d_in[11];
    const float* av = (const float*)d_in[12];
    const float* Wx = (const float*)d_in[13];
    const float* xg = (const float*)d_in[14];
    const float* xb = (const float*)d_in[15];
    const float* xm = (const float*)d_in[16];
    const float* xv = (const float*)d_in[17];
    const float* Wr = (const float*)d_in[18];
    const float* rg = (const float*)d_in[19];
    const float* rb = (const float*)d_in[20];
    const float* rm = (const float*)d_in[21];
    const float* rv = (const float*)d_in[22];
    const int* gidx = (const int*)d_in[23];
    const int* gcnt = (const int*)d_in[24];
    float* out = (float*)d_out;

    char* ws = (char*)d_ws;
    unsigned* Sfa  = (unsigned*)ws;                      // 16 MiB real
    unsigned* Sfa2 = (unsigned*)(ws + (32u << 20));      // diag scratch
    float*    out2 = (float*)(ws + (64u << 20));         // diag scratch

    // ---- real path (identical to R8) ----
    pt_enc<1><<<dim3(Bc * Nc / 64), dim3(256), 0, stream>>>(
        feats, xyz, Wf, Wa, Wx,
        fg, fb, fm, fv, ag, ab, am, av, xg, xb, xm, xv, Sfa);
    pt_gr5<1><<<dim3((Bc * Mc) / 16), dim3(512), 0, stream>>>(
        nxyz, Sfa, Wr, rg, rb, rm, rv, Wx, xg, xb, xm, xv,
        gidx, gcnt, out);

    // ---- diagnostic repeats (counters visibility; stripped next round) ----
    pt_enc<8><<<dim3(Bc * Nc / 64), dim3(256), 0, stream>>>(
        feats, xyz, Wf, Wa, Wx,
        fg, fb, fm, fv, ag, ab, am, av, xg, xb, xm, xv, Sfa2);
    pt_gr5<4><<<dim3((Bc * Mc) / 16), dim3(512), 0, stream>>>(
        nxyz, Sfa, Wr, rg, rb, rm, rv, Wx, xg, xb, xm, xv,
        gidx, gcnt, out2);
}

// Round 10
// 42.765 us; speedup vs baseline: 2.6016x; 2.6016x over previous
//
#include <hip/hip_runtime.h>

constexpr int Bc = 4, Nc = 16384, Mc = 4096, Kc = 32;
constexpr float EPSc = 1e-5f;
constexpr float L2E = 1.4426950408889634f;   // log2(e)

using bf16x8 = __attribute__((ext_vector_type(8))) short;   // 8 bf16 (4 VGPRs)
using f32x4  = __attribute__((ext_vector_type(4))) float;   // 4 fp32

__device__ inline unsigned f2bf_bits(float x) {
    unsigned u = __float_as_uint(x);
    return (u + 0x7fffu + ((u >> 16) & 1u)) >> 16;
}
__device__ inline short f2bf(float x) { return (short)f2bf_bits(x); }

// ---------------------------------------------------------------------------
// pt_prep (32 blocks, parallel): bake scaled+transposed bf16 weight tables and
// folded BN vectors. WfaT[c][k] (c<64: feat*BNscale*log2e, c>=64: attn*BNscale),
// WrT[c][k] (refine*BNscale), bis_enc[128], bisg[128], cw[64]={w0,w1,w2,P}.
// ---------------------------------------------------------------------------
__global__ __launch_bounds__(256) void pt_prep(
    const float* __restrict__ Wf, const float* __restrict__ Wa,
    const float* __restrict__ Wr, const float* __restrict__ Wx,
    const float* __restrict__ fg, const float* __restrict__ fb,
    const float* __restrict__ fm, const float* __restrict__ fv,
    const float* __restrict__ ag, const float* __restrict__ ab,
    const float* __restrict__ am, const float* __restrict__ av,
    const float* __restrict__ xg, const float* __restrict__ xb,
    const float* __restrict__ xm, const float* __restrict__ xv,
    const float* __restrict__ rg, const float* __restrict__ rb,
    const float* __restrict__ rm, const float* __restrict__ rv,
    short* __restrict__ WfaT, short* __restrict__ WrT,
    float* __restrict__ bis_enc, float* __restrict__ bisg,
    float* __restrict__ cw)
{
    const int tid = threadIdx.x;
    const int i = blockIdx.x * 256 + tid;            // 0..8191
    const int c = i >> 6, k = i & 63;                // [c][k]
    float s, wv;
    if (c < 64) { s = fg[c] * rsqrtf(fv[c] + EPSc) * L2E; wv = Wf[k * 64 + c]; }
    else { const int c2 = c - 64; s = ag[c2] * rsqrtf(av[c2] + EPSc); wv = Wa[k * 64 + c2]; }
    WfaT[i] = f2bf(wv * s);
    WrT[i]  = f2bf(Wr[k * 128 + c] * (rg[c] * rsqrtf(rv[c] + EPSc)));

    if (blockIdx.x == 0) {
        if (tid < 128) {
            const int cc = tid & 63;
            const float g  = (tid < 64) ? fg[cc] : ag[cc];
            const float v  = (tid < 64) ? fv[cc] : av[cc];
            const float bb = (tid < 64) ? fb[cc] : ab[cc];
            const float mm = (tid < 64) ? fm[cc] : am[cc];
            const float sc = g * rsqrtf(v + EPSc);
            bis_enc[tid] = (tid < 64) ? (bb - mm * sc) * L2E : (bb - mm * sc);
            bisg[tid] = rb[tid] - rm[tid] * (rg[tid] * rsqrtf(rv[tid] + EPSc));
        }
        if (tid < 64) {
            const float xs = xg[tid] * rsqrtf(xv[tid] + EPSc);
            *(float4*)(cw + tid * 4) = make_float4(
                Wx[tid] * xs, Wx[64 + tid] * xs, Wx[128 + tid] * xs,
                xb[tid] - xm[tid] * xs);
        }
    }
}

// ---------------------------------------------------------------------------
// pt_enc (MFMA): Sfa[n][c] = pack( hi = bf16((f_bn + dot(x_n,w_c))*log2e),
//                                  lo = bf16(a_bn + dot(x_n,w_c)) )
// B fragments from prebaked global WfaT (16 KB, L1-hot); no weight staging.
// C-write through LDS transpose tile -> 16 coalesced 256B row stores/wave.
// ---------------------------------------------------------------------------
__global__ __launch_bounds__(256) void pt_enc(
    const float* __restrict__ feats, const float* __restrict__ xyz,
    const short* __restrict__ WfaT, const float* __restrict__ bis_enc,
    const float* __restrict__ cw, unsigned* __restrict__ Sfa)
{
    __shared__ unsigned stile[4][16][68];         // transpose tile per wave
    __shared__ float sx[64][3];                   // block's 64 points' xyz
    const int tid = threadIdx.x, lane = tid & 63, w = tid >> 6;
    const int row16 = lane & 15, kg = lane >> 4;
    const long long row0 = (long long)blockIdx.x * 64;

    if (tid < 192) ((float*)sx)[tid] = xyz[row0 * 3 + tid];

    bf16x8 bfr[8][2];
#pragma unroll
    for (int t = 0; t < 8; ++t)
#pragma unroll
        for (int h = 0; h < 2; ++h)
            bfr[t][h] = *(const bf16x8*)(WfaT + (16 * t + row16) * 64 + 32 * h + kg * 8);

    const long long base = row0 + w * 16;
    const float* arow = feats + (base + row16) * 64 + kg * 8;
    const float4 v0 = *(const float4*)(arow + 0);
    const float4 v1 = *(const float4*)(arow + 4);
    const float4 v2 = *(const float4*)(arow + 32);
    const float4 v3 = *(const float4*)(arow + 36);
    bf16x8 af0, af1;
    af0[0]=f2bf(v0.x); af0[1]=f2bf(v0.y); af0[2]=f2bf(v0.z); af0[3]=f2bf(v0.w);
    af0[4]=f2bf(v1.x); af0[5]=f2bf(v1.y); af0[6]=f2bf(v1.z); af0[7]=f2bf(v1.w);
    af1[0]=f2bf(v2.x); af1[1]=f2bf(v2.y); af1[2]=f2bf(v2.z); af1[3]=f2bf(v2.w);
    af1[4]=f2bf(v3.x); af1[5]=f2bf(v3.y); af1[6]=f2bf(v3.z); af1[7]=f2bf(v3.w);

    f32x4 acc[8];
#pragma unroll
    for (int t = 0; t < 8; ++t) {
        f32x4 z = {0.f, 0.f, 0.f, 0.f};
        z = __builtin_amdgcn_mfma_f32_16x16x32_bf16(af0, bfr[t][0], z, 0, 0, 0);
        z = __builtin_amdgcn_mfma_f32_16x16x32_bf16(af1, bfr[t][1], z, 0, 0, 0);
        acc[t] = z;
    }
    __syncthreads();                              // sx visible

    float4 cwt[4];
#pragma unroll
    for (int t = 0; t < 4; ++t)
        cwt[t] = *(const float4*)(cw + (16 * t + row16) * 4);

    const int lrow = w * 16 + kg * 4;
    // C/D layout: row=(lane>>4)*4+reg, col=lane&15 -> LDS tile -> coalesced
#pragma unroll
    for (int r = 0; r < 4; ++r) {
        const float x0 = sx[lrow + r][0], x1 = sx[lrow + r][1], x2 = sx[lrow + r][2];
#pragma unroll
        for (int t = 0; t < 4; ++t) {
            const int c = 16 * t + row16;
            const float px = fmaf(x0, cwt[t].x, fmaf(x1, cwt[t].y, x2 * cwt[t].z));
            stile[w][kg * 4 + r][c] =
                  f2bf_bits(acc[t + 4][r] + bis_enc[64 + c] + px)
                | (f2bf_bits(acc[t][r] + bis_enc[c] + px * L2E) << 16);
        }
    }
    __syncthreads();
#pragma unroll
    for (int rr = 0; rr < 16; ++rr)
        Sfa[(base + rr) * 64 + lane] = stile[w][rr][lane];
}

// ---------------------------------------------------------------------------
// pt_gr6: 512 thr = 8 waves, 2 groups/wave (16/block), 1024 blocks.
// readlane -> SGPR index -> SALU gather addressing. Softmax shift-invariance:
// Q factored OUT of the exponent and applied once at the end -> 5 VALU/group-k.
// B-fragments direct from prebaked global WrT (no LDS staging, no extra
// barrier). XCD-pinned swizzle (batch -> XCD pair). LDS = snf only (2.3 KB).
// ---------------------------------------------------------------------------
__global__ __launch_bounds__(512) void pt_gr6(
    const float* __restrict__ nxyz, const unsigned* __restrict__ Sfa,
    const short* __restrict__ WrT, const float* __restrict__ bisg,
    const float* __restrict__ cw, const int* __restrict__ gidx,
    const int* __restrict__ gcnt, float* __restrict__ out)
{
    __shared__ __align__(16) short snf[16][72];   // softmax outputs [group][ch]

    const int tid = threadIdx.x, lane = tid & 63, w = tid >> 6;
    const int row16 = lane & 15, kg = lane >> 4;
    // bijective XCD-pinning swizzle: xcd = blk%8 serves batch (blk%8)>>1
    const int i = blockIdx.x;                     // 0..1023
    const int b = (i & 7) >> 1;
    const int j = ((i >> 3) << 1) | (i & 1);      // 0..255
    const long long gbase = (long long)b * Mc + j * 16;

    // both groups' neighbor lists in one coalesced 64-int load (wave-local)
    const int nv = gidx[(gbase + 2 * w) * 32 + lane];

    // per-lane channel coeffs + per-group constants
    const float4 cwl = *(const float4*)(cw + lane * 4);  // w0,w1,w2,P
    const float* nx = nxyz + (gbase + 2 * w) * 3;  // 6 floats = both groups
    const float QA = cwl.w - fmaf(nx[0], cwl.x, fmaf(nx[1], cwl.y, nx[2] * cwl.z));
    const float QB = cwl.w - fmaf(nx[3], cwl.x, fmaf(nx[4], cwl.y, nx[5] * cwl.z));

    // refine B-fragments issued early (L1-hot 16 KB table)
    const bf16x8 bf0 = *(const bf16x8*)(WrT + (16 * w + row16) * 64 + kg * 8);
    const bf16x8 bf1 = *(const bf16x8*)(WrT + (16 * w + row16) * 64 + 32 + kg * 8);

    const unsigned* sbase = Sfa + (long long)b * (Nc * 64) + lane;
    float ssA = 0.f, acA = 0.f, ssB = 0.f, acB = 0.f;
#pragma unroll
    for (int k = 0; k < Kc; ++k) {
        const int nA = __builtin_amdgcn_readlane(nv, k);        // SGPR index
        const int nB = __builtin_amdgcn_readlane(nv, 32 + k);
        const unsigned dA = sbase[nA << 6];        // SALU-addressed 256B gather
        const unsigned dB = sbase[nB << 6];
        // weights invariant to the per-(group,ch) shift Q: u = exp2(hi)
        const float uA = __builtin_amdgcn_exp2f(__uint_as_float(dA & 0xffff0000u));
        const float uB = __builtin_amdgcn_exp2f(__uint_as_float(dB & 0xffff0000u));
        const float aA = __uint_as_float(dA << 16);
        const float aB = __uint_as_float(dB << 16);
        ssA += uA; acA = fmaf(uA, aA, acA);
        ssB += uB; acB = fmaf(uB, aB, acB);
    }
    snf[2 * w][lane]     = f2bf(fmaf(acA, __builtin_amdgcn_rcpf(ssA), QA));
    snf[2 * w + 1][lane] = f2bf(fmaf(acB, __builtin_amdgcn_rcpf(ssB), QB));
    __syncthreads();

    // refine MFMA: A = snf (16 rows), B = WrT col-tile w
    const bf16x8 af0 = *(const bf16x8*)&snf[row16][kg * 8];
    const bf16x8 af1 = *(const bf16x8*)&snf[row16][32 + kg * 8];
    f32x4 z = {0.f, 0.f, 0.f, 0.f};
    z = __builtin_amdgcn_mfma_f32_16x16x32_bf16(af0, bf0, z, 0, 0, 0);
    z = __builtin_amdgcn_mfma_f32_16x16x32_bf16(af1, bf1, z, 0, 0, 0);

    // epilogue: BN+ReLU+mask (bisg prebaked; per-lane channel cc)
    const int4 c4 = *(const int4*)(gcnt + gbase + kg * 4);
    const int cc = 16 * w + row16;
    const float bb = bisg[cc];
    float* orow = out + (gbase + kg * 4) * 128 + cc;
    __builtin_nontemporal_store(fmaxf(z[0] + bb, 0.f) * (c4.x > 0 ? 1.f : 0.f), orow);
    __builtin_nontemporal_store(fmaxf(z[1] + bb, 0.f) * (c4.y > 0 ? 1.f : 0.f), orow + 128);
    __builtin_nontemporal_store(fmaxf(z[2] + bb, 0.f) * (c4.z > 0 ? 1.f : 0.f), orow + 256);
    __builtin_nontemporal_store(fmaxf(z[3] + bb, 0.f) * (c4.w > 0 ? 1.f : 0.f), orow + 384);
}

extern "C" void kernel_launch(void* const* d_in, const int* in_sizes, int n_in,
                              void* d_out, int out_size, void* d_ws, size_t ws_size,
                              hipStream_t stream)
{
    const float* xyz  = (const float*)d_in[0];
    const float* nxyz = (const float*)d_in[1];
    const float* feats = (const float*)d_in[2];
    const float* Wf = (const float*)d_in[3];
    const float* fg = (const float*)d_in[4];
    const float* fb = (const float*)d_in[5];
    const float* fm = (const float*)d_in[6];
    const float* fv = (const float*)d_in[7];
    const float* Wa = (const float*)d_in[8];
    const float* ag = (const float*)d_in[9];
    const float* ab = (const float*)d_in[10];
    const float* am = (const float*)d_in[11];
    const float* av = (const float*)d_in[12];
    const float* Wx = (const float*)d_in[13];
    const float* xg = (const float*)d_in[14];
    const float* xb = (const float*)d_in[15];
    const float* xm = (const float*)d_in[16];
    const float* xv = (const float*)d_in[17];
    const float* Wr = (const float*)d_in[18];
    const float* rg = (const float*)d_in[19];
    const float* rb = (const float*)d_in[20];
    const float* rm = (const float*)d_in[21];
    const float* rv = (const float*)d_in[22];
    const int* gidx = (const int*)d_in[23];
    const int* gcnt = (const int*)d_in[24];
    float* out = (float*)d_out;

    char* ws = (char*)d_ws;
    const size_t SFA_B = (size_t)Bc * Nc * 64 * 4;       // 16 MiB
    unsigned* Sfa  = (unsigned*)ws;
    short* WfaT    = (short*)(ws + SFA_B);
    short* WrT     = (short*)(ws + SFA_B + 16384);
    float* bis_enc = (float*)(ws + SFA_B + 32768);
    float* bisg    = (float*)(ws + SFA_B + 33280);
    float* cw      = (float*)(ws + SFA_B + 33792);

    pt_prep<<<dim3(32), dim3(256), 0, stream>>>(
        Wf, Wa, Wr, Wx, fg, fb, fm, fv, ag, ab, am, av,
        xg, xb, xm, xv, rg, rb, rm, rv, WfaT, WrT, bis_enc, bisg, cw);
    pt_enc<<<dim3(Bc * Nc / 64), dim3(256), 0, stream>>>(
        feats, xyz, WfaT, bis_enc, cw, Sfa);
    pt_gr6<<<dim3((Bc * Mc) / 16), dim3(512), 0, stream>>>(
        nxyz, Sfa, WrT, bisg, cw, gidx, gcnt, out);
}

// Round 11
// 33.863 us; speedup vs baseline: 3.2856x; 1.2629x over previous
//
#include <hip/hip_runtime.h>

constexpr int Bc = 4, Nc = 16384, Mc = 4096, Kc = 32;
constexpr float EPSc = 1e-5f;
constexpr float L2E = 1.4426950408889634f;   // log2(e)

using bf16x8 = __attribute__((ext_vector_type(8))) short;   // 8 bf16 (4 VGPRs)
using f32x4  = __attribute__((ext_vector_type(4))) float;   // 4 fp32

__device__ inline unsigned f2bf_bits(float x) {
    unsigned u = __float_as_uint(x);
    return (u + 0x7fffu + ((u >> 16) & 1u)) >> 16;
}
__device__ inline short f2bf(float x) { return (short)f2bf_bits(x); }

// ---------------------------------------------------------------------------
// pt_enc (MFMA): Sfa[n][c] = pack( hi = bf16((f_bn + dot(x_n,w_c))*log2e),
//                                  lo = bf16(a_bn + dot(x_n,w_c)) )
// Self-contained (R8 structure): stages scaled bf16 W^T per block, folds the
// neighbor xyz term, writes C through an LDS transpose tile -> 16 coalesced
// 256B row stores per wave.
// ---------------------------------------------------------------------------
__global__ __launch_bounds__(256) void pt_enc(
    const float* __restrict__ feats, const float* __restrict__ xyz,
    const float* __restrict__ Wf, const float* __restrict__ Wa,
    const float* __restrict__ Wx,
    const float* __restrict__ fg, const float* __restrict__ fb,
    const float* __restrict__ fm, const float* __restrict__ fv,
    const float* __restrict__ ag, const float* __restrict__ ab,
    const float* __restrict__ am, const float* __restrict__ av,
    const float* __restrict__ xg, const float* __restrict__ xb,
    const float* __restrict__ xm, const float* __restrict__ xv,
    unsigned* __restrict__ Sfa)
{
    __shared__ __align__(16) short WT[128][72];   // [col][k]
    __shared__ unsigned stile[4][16][68];         // transpose tile per wave
    __shared__ float  sx[64][3];                  // block's 64 points' xyz
    __shared__ float4 scw[64];                    // per-channel {w0,w1,w2,-}
    __shared__ float  bis[128];

    const int tid = threadIdx.x, lane = tid & 63, w = tid >> 6;
    const int row16 = lane & 15, kg = lane >> 4;
    const long long row0 = (long long)blockIdx.x * 64;

    if (tid < 192) ((float*)sx)[tid] = xyz[row0 * 3 + tid];
    if (tid < 64) {
        const float xs = xg[tid] * rsqrtf(xv[tid] + EPSc);
        scw[tid] = make_float4(Wx[tid] * xs, Wx[64 + tid] * xs,
                               Wx[128 + tid] * xs, 0.f);
    }
    if (tid < 128) {
        const int c = tid & 63;
        const float g  = (tid < 64) ? fg[c] : ag[c];
        const float v  = (tid < 64) ? fv[c] : av[c];
        const float bb = (tid < 64) ? fb[c] : ab[c];
        const float mm = (tid < 64) ? fm[c] : am[c];
        const float s = g * rsqrtf(v + EPSc);
        bis[tid] = (tid < 64) ? (bb - mm * s) * L2E : (bb - mm * s);
    }
    {   // WT staging: thread owns channel c = tid&63 for both planes
        const int c = tid & 63, k0 = tid >> 6;
        const float sf = fg[c] * rsqrtf(fv[c] + EPSc) * L2E;
        const float sa = ag[c] * rsqrtf(av[c] + EPSc);
#pragma unroll
        for (int it = 0; it < 16; ++it) {
            const int k = k0 + 4 * it;
            WT[c][k]      = f2bf(Wf[k * 64 + c] * sf);
            WT[64 + c][k] = f2bf(Wa[k * 64 + c] * sa);
        }
    }
    __syncthreads();

    bf16x8 bfr[8][2];
#pragma unroll
    for (int t = 0; t < 8; ++t)
#pragma unroll
        for (int h = 0; h < 2; ++h)
            bfr[t][h] = *(const bf16x8*)&WT[16 * t + row16][32 * h + kg * 8];

    const long long base = row0 + w * 16;
    const float* arow = feats + (base + row16) * 64 + kg * 8;
    const float4 v0 = *(const float4*)(arow + 0);
    const float4 v1 = *(const float4*)(arow + 4);
    const float4 v2 = *(const float4*)(arow + 32);
    const float4 v3 = *(const float4*)(arow + 36);
    bf16x8 af0, af1;
    af0[0]=f2bf(v0.x); af0[1]=f2bf(v0.y); af0[2]=f2bf(v0.z); af0[3]=f2bf(v0.w);
    af0[4]=f2bf(v1.x); af0[5]=f2bf(v1.y); af0[6]=f2bf(v1.z); af0[7]=f2bf(v1.w);
    af1[0]=f2bf(v2.x); af1[1]=f2bf(v2.y); af1[2]=f2bf(v2.z); af1[3]=f2bf(v2.w);
    af1[4]=f2bf(v3.x); af1[5]=f2bf(v3.y); af1[6]=f2bf(v3.z); af1[7]=f2bf(v3.w);

    f32x4 acc[8];
#pragma unroll
    for (int t = 0; t < 8; ++t) {
        f32x4 z = {0.f, 0.f, 0.f, 0.f};
        z = __builtin_amdgcn_mfma_f32_16x16x32_bf16(af0, bfr[t][0], z, 0, 0, 0);
        z = __builtin_amdgcn_mfma_f32_16x16x32_bf16(af1, bfr[t][1], z, 0, 0, 0);
        acc[t] = z;
    }

    // per-lane xyz-proj coeffs for this lane's 4 output cols
    float4 cwt[4];
#pragma unroll
    for (int t = 0; t < 4; ++t)
        cwt[t] = scw[16 * t + row16];

    const int lrow = w * 16 + kg * 4;
    // C/D layout: row=(lane>>4)*4+reg, col=lane&15 -> LDS tile -> coalesced
#pragma unroll
    for (int r = 0; r < 4; ++r) {
        const float x0 = sx[lrow + r][0], x1 = sx[lrow + r][1], x2 = sx[lrow + r][2];
#pragma unroll
        for (int t = 0; t < 4; ++t) {
            const int c = 16 * t + row16;
            const float px = fmaf(x0, cwt[t].x, fmaf(x1, cwt[t].y, x2 * cwt[t].z));
            stile[w][kg * 4 + r][c] =
                  f2bf_bits(acc[t + 4][r] + bis[64 + c] + px)
                | (f2bf_bits(acc[t][r] + bis[c] + px * L2E) << 16);
        }
    }
    __syncthreads();
#pragma unroll
    for (int rr = 0; rr < 16; ++rr)
        Sfa[(base + rr) * 64 + lane] = stile[w][rr][lane];
}

// ---------------------------------------------------------------------------
// pt_gr7: R8's pt_gr5 + softmax shift-invariance. 512 thr = 8 waves,
// 2 groups/wave (16/block), 1024 blocks. readlane -> SGPR index -> SALU
// gather addressing. Weights u = exp2(hi) only (group constant Q cancels in
// the softmax ratio); Q applied ONCE at the end: snf = ac/ss + Q.
// Inner loop: 5 VALU per group-k (was 7). XCD-pinned swizzle.
// ---------------------------------------------------------------------------
__global__ __launch_bounds__(512) void pt_gr7(
    const float* __restrict__ nxyz, const unsigned* __restrict__ Sfa,
    const float* __restrict__ Wr,
    const float* __restrict__ rg, const float* __restrict__ rb,
    const float* __restrict__ rm, const float* __restrict__ rv,
    const float* __restrict__ Wx,
    const float* __restrict__ xg, const float* __restrict__ xb,
    const float* __restrict__ xm, const float* __restrict__ xv,
    const int* __restrict__ gidx, const int* __restrict__ gcnt,
    float* __restrict__ out)
{
    __shared__ __align__(16) short WT[128][72];   // refine weights [col][k]
    __shared__ __align__(16) short snf[16][72];   // softmax outputs [group][ch]

    const int tid = threadIdx.x, lane = tid & 63, w = tid >> 6;
    const int row16 = lane & 15, kg = lane >> 4;
    // bijective XCD-pinning swizzle: xcd = blk%8 serves batch (blk%8)>>1
    const int i = blockIdx.x;                     // 0..1023
    const int b = (i & 7) >> 1;
    const int j = ((i >> 3) << 1) | (i & 1);      // 0..255
    const long long gbase = (long long)b * Mc + j * 16;

    // both groups' neighbor lists in one coalesced 64-int load (wave-local)
    const int nv = gidx[(gbase + 2 * w) * 32 + lane];

    {   // WT staging: thread owns channel c = tid&127 (scale in registers)
        const int c = tid & 127, k0 = tid >> 7;
        const float sr = rg[c] * rsqrtf(rv[c] + EPSc);
#pragma unroll
        for (int it = 0; it < 16; ++it) {
            const int k = k0 + 4 * it;
            WT[c][k] = f2bf(Wr[k * 128 + c] * sr);
        }
    }

    // per-lane channel coeffs (channel = lane) + per-group constants
    const float xs = xg[lane] * rsqrtf(xv[lane] + EPSc);
    const float w0 = Wx[lane] * xs, w1 = Wx[64 + lane] * xs, w2 = Wx[128 + lane] * xs;
    const float P = xb[lane] - xm[lane] * xs;
    const float* nx = nxyz + (gbase + 2 * w) * 3;  // 6 floats = both groups
    const float QA = P - fmaf(nx[0], w0, fmaf(nx[1], w1, nx[2] * w2));
    const float QB = P - fmaf(nx[3], w0, fmaf(nx[4], w1, nx[5] * w2));

    const unsigned* sbase = Sfa + (long long)b * (Nc * 64) + lane;
    float ssA = 0.f, acA = 0.f, ssB = 0.f, acB = 0.f;
#pragma unroll
    for (int k = 0; k < Kc; ++k) {
        const int nA = __builtin_amdgcn_readlane(nv, k);        // SGPR index
        const int nB = __builtin_amdgcn_readlane(nv, 32 + k);
        const unsigned dA = sbase[nA << 6];        // SALU-addressed 256B gather
        const unsigned dB = sbase[nB << 6];
        // shift-invariance: u = exp2(hi) (Q cancels in the ratio)
        const float uA = __builtin_amdgcn_exp2f(__uint_as_float(dA & 0xffff0000u));
        const float uB = __builtin_amdgcn_exp2f(__uint_as_float(dB & 0xffff0000u));
        const float aA = __uint_as_float(dA << 16);
        const float aB = __uint_as_float(dB << 16);
        ssA += uA; acA = fmaf(uA, aA, acA);
        ssB += uB; acB = fmaf(uB, aB, acB);
    }
    snf[2 * w][lane]     = f2bf(fmaf(acA, __builtin_amdgcn_rcpf(ssA), QA));
    snf[2 * w + 1][lane] = f2bf(fmaf(acB, __builtin_amdgcn_rcpf(ssB), QB));
    __syncthreads();

    // refine MFMA: A = snf (16 rows), B = WT col-tile w
    const bf16x8 af0 = *(const bf16x8*)&snf[row16][kg * 8];
    const bf16x8 af1 = *(const bf16x8*)&snf[row16][32 + kg * 8];
    const bf16x8 bf0 = *(const bf16x8*)&WT[16 * w + row16][kg * 8];
    const bf16x8 bf1 = *(const bf16x8*)&WT[16 * w + row16][32 + kg * 8];
    f32x4 z = {0.f, 0.f, 0.f, 0.f};
    z = __builtin_amdgcn_mfma_f32_16x16x32_bf16(af0, bf0, z, 0, 0, 0);
    z = __builtin_amdgcn_mfma_f32_16x16x32_bf16(af1, bf1, z, 0, 0, 0);

    // epilogue: BN+ReLU+mask; per-lane channel cc fixed -> scale in registers
    const int4 c4 = *(const int4*)(gcnt + gbase + kg * 4);
    const int cc = 16 * w + row16;
    const float sr = rg[cc] * rsqrtf(rv[cc] + EPSc);
    const float bb = rb[cc] - rm[cc] * sr;
    float* orow = out + (gbase + kg * 4) * 128 + cc;
    __builtin_nontemporal_store(fmaxf(z[0] + bb, 0.f) * (c4.x > 0 ? 1.f : 0.f), orow);
    __builtin_nontemporal_store(fmaxf(z[1] + bb, 0.f) * (c4.y > 0 ? 1.f : 0.f), orow + 128);
    __builtin_nontemporal_store(fmaxf(z[2] + bb, 0.f) * (c4.z > 0 ? 1.f : 0.f), orow + 256);
    __builtin_nontemporal_store(fmaxf(z[3] + bb, 0.f) * (c4.w > 0 ? 1.f : 0.f), orow + 384);
}

extern "C" void kernel_launch(void* const* d_in, const int* in_sizes, int n_in,
                              void* d_out, int out_size, void* d_ws, size_t ws_size,
                              hipStream_t stream)
{
    const float* xyz  = (const float*)d_in[0];
    const float* nxyz = (const float*)d_in[1];
    const float* feats = (const float*)d_in[2];
    const float* Wf = (const float*)d_in[3];
    const float* fg = (const float*)d_in[4];
    const float* fb = (const float*)d_in[5];
    const float* fm = (const float*)d_in[6];
    const float* fv = (const float*)d_in[7];
    const float* Wa = (const float*)d_in[8];
    const float* ag = (const float*)d_in[9];
    const float* ab = (const float*)d_in[10];
    const float* am = (const float*)d_in[11];
    const float* av = (const float*)d_in[12];
    const float* Wx = (const float*)d_in[13];
    const float* xg = (const float*)d_in[14];
    const float* xb = (const float*)d_in[15];
    const float* xm = (const float*)d_in[16];
    const float* xv = (const float*)d_in[17];
    const float* Wr = (const float*)d_in[18];
    const float* rg = (const float*)d_in[19];
    const float* rb = (const float*)d_in[20];
    const float* rm = (const float*)d_in[21];
    const float* rv = (const float*)d_in[22];
    const int* gidx = (const int*)d_in[23];
    const int* gcnt = (const int*)d_in[24];
    float* out = (float*)d_out;

    unsigned* Sfa = (unsigned*)d_ws;   // B*N*64 dwords = 16 MiB packed bf16 pairs

    pt_enc<<<dim3(Bc * Nc / 64), dim3(256), 0, stream>>>(
        feats, xyz, Wf, Wa, Wx,
        fg, fb, fm, fv, ag, ab, am, av, xg, xb, xm, xv, Sfa);
    pt_gr7<<<dim3((Bc * Mc) / 16), dim3(512), 0, stream>>>(
        nxyz, Sfa, Wr, rg, rb, rm, rv, Wx, xg, xb, xm, xv,
        gidx, gcnt, out);
}

// Round 12
// 28.720 us; speedup vs baseline: 3.8740x; 1.1791x over previous
//
#include <hip/hip_runtime.h>

constexpr int Bc = 4, Nc = 16384, Mc = 4096, Kc = 32;
constexpr float EPSc = 1e-5f;
constexpr float L2E = 1.4426950408889634f;   // log2(e)

using bf16x8 = __attribute__((ext_vector_type(8))) short;   // 8 bf16 (4 VGPRs)
using f32x4  = __attribute__((ext_vector_type(4))) float;   // 4 fp32

__device__ inline unsigned f2bf_bits(float x) {
    unsigned u = __float_as_uint(x);
    return (u + 0x7fffu + ((u >> 16) & 1u)) >> 16;
}
__device__ inline short f2bf(float x) { return (short)f2bf_bits(x); }

// ---------------------------------------------------------------------------
// pt_enc (MFMA): Sfa[n][c] = pack( hi = bf16((f_bn + dot(x_n,w_c))*log2e),
//                                  lo = bf16(a_bn + dot(x_n,w_c)) )
// NEW: batch->XCD-pair pinned block swizzle IDENTICAL to pt_gr7, so the Sfa
// lines this kernel writes stay dirty in exactly the L2s the gather kernel
// reads them from (producer-consumer L2 locality across the launch boundary).
// ---------------------------------------------------------------------------
__global__ __launch_bounds__(256) void pt_enc(
    const float* __restrict__ feats, const float* __restrict__ xyz,
    const float* __restrict__ Wf, const float* __restrict__ Wa,
    const float* __restrict__ Wx,
    const float* __restrict__ fg, const float* __restrict__ fb,
    const float* __restrict__ fm, const float* __restrict__ fv,
    const float* __restrict__ ag, const float* __restrict__ ab,
    const float* __restrict__ am, const float* __restrict__ av,
    const float* __restrict__ xg, const float* __restrict__ xb,
    const float* __restrict__ xm, const float* __restrict__ xv,
    unsigned* __restrict__ Sfa)
{
    __shared__ __align__(16) short WT[128][72];   // [col][k]
    __shared__ unsigned stile[4][16][68];         // transpose tile per wave
    __shared__ float  sx[64][3];                  // block's 64 points' xyz
    __shared__ float4 scw[64];                    // per-channel {w0,w1,w2,-}
    __shared__ float  bis[128];

    const int tid = threadIdx.x, lane = tid & 63, w = tid >> 6;
    const int row16 = lane & 15, kg = lane >> 4;
    // bijective XCD-pinning swizzle (matches pt_gr7): xcd=blk%8 -> batch (blk%8)>>1
    const int i = blockIdx.x;                     // 0..1023
    const int b = (i & 7) >> 1;
    const int j = ((i >> 3) << 1) | (i & 1);      // 0..255 tile within batch
    const long long row0 = ((long long)b * 256 + j) * 64;

    if (tid < 192) ((float*)sx)[tid] = xyz[row0 * 3 + tid];
    if (tid < 64) {
        const float xs = xg[tid] * rsqrtf(xv[tid] + EPSc);
        scw[tid] = make_float4(Wx[tid] * xs, Wx[64 + tid] * xs,
                               Wx[128 + tid] * xs, 0.f);
    }
    if (tid < 128) {
        const int c = tid & 63;
        const float g  = (tid < 64) ? fg[c] : ag[c];
        const float v  = (tid < 64) ? fv[c] : av[c];
        const float bb = (tid < 64) ? fb[c] : ab[c];
        const float mm = (tid < 64) ? fm[c] : am[c];
        const float s = g * rsqrtf(v + EPSc);
        bis[tid] = (tid < 64) ? (bb - mm * s) * L2E : (bb - mm * s);
    }
    {   // WT staging: thread owns channel c = tid&63 for both planes
        const int c = tid & 63, k0 = tid >> 6;
        const float sf = fg[c] * rsqrtf(fv[c] + EPSc) * L2E;
        const float sa = ag[c] * rsqrtf(av[c] + EPSc);
#pragma unroll
        for (int it = 0; it < 16; ++it) {
            const int k = k0 + 4 * it;
            WT[c][k]      = f2bf(Wf[k * 64 + c] * sf);
            WT[64 + c][k] = f2bf(Wa[k * 64 + c] * sa);
        }
    }
    __syncthreads();

    bf16x8 bfr[8][2];
#pragma unroll
    for (int t = 0; t < 8; ++t)
#pragma unroll
        for (int h = 0; h < 2; ++h)
            bfr[t][h] = *(const bf16x8*)&WT[16 * t + row16][32 * h + kg * 8];

    const long long base = row0 + w * 16;
    const float* arow = feats + (base + row16) * 64 + kg * 8;
    const float4 v0 = *(const float4*)(arow + 0);
    const float4 v1 = *(const float4*)(arow + 4);
    const float4 v2 = *(const float4*)(arow + 32);
    const float4 v3 = *(const float4*)(arow + 36);
    bf16x8 af0, af1;
    af0[0]=f2bf(v0.x); af0[1]=f2bf(v0.y); af0[2]=f2bf(v0.z); af0[3]=f2bf(v0.w);
    af0[4]=f2bf(v1.x); af0[5]=f2bf(v1.y); af0[6]=f2bf(v1.z); af0[7]=f2bf(v1.w);
    af1[0]=f2bf(v2.x); af1[1]=f2bf(v2.y); af1[2]=f2bf(v2.z); af1[3]=f2bf(v2.w);
    af1[4]=f2bf(v3.x); af1[5]=f2bf(v3.y); af1[6]=f2bf(v3.z); af1[7]=f2bf(v3.w);

    f32x4 acc[8];
#pragma unroll
    for (int t = 0; t < 8; ++t) {
        f32x4 z = {0.f, 0.f, 0.f, 0.f};
        z = __builtin_amdgcn_mfma_f32_16x16x32_bf16(af0, bfr[t][0], z, 0, 0, 0);
        z = __builtin_amdgcn_mfma_f32_16x16x32_bf16(af1, bfr[t][1], z, 0, 0, 0);
        acc[t] = z;
    }

    // per-lane xyz-proj coeffs for this lane's 4 output cols
    float4 cwt[4];
#pragma unroll
    for (int t = 0; t < 4; ++t)
        cwt[t] = scw[16 * t + row16];

    const int lrow = w * 16 + kg * 4;
    // C/D layout: row=(lane>>4)*4+reg, col=lane&15 -> LDS tile -> coalesced
#pragma unroll
    for (int r = 0; r < 4; ++r) {
        const float x0 = sx[lrow + r][0], x1 = sx[lrow + r][1], x2 = sx[lrow + r][2];
#pragma unroll
        for (int t = 0; t < 4; ++t) {
            const int c = 16 * t + row16;
            const float px = fmaf(x0, cwt[t].x, fmaf(x1, cwt[t].y, x2 * cwt[t].z));
            stile[w][kg * 4 + r][c] =
                  f2bf_bits(acc[t + 4][r] + bis[64 + c] + px)
                | (f2bf_bits(acc[t][r] + bis[c] + px * L2E) << 16);
        }
    }
    __syncthreads();
#pragma unroll
    for (int rr = 0; rr < 16; ++rr)
        Sfa[(base + rr) * 64 + lane] = stile[w][rr][lane];
}

// ---------------------------------------------------------------------------
// pt_gr7 (unchanged from R11): 512 thr = 8 waves, 2 groups/wave, 1024 blocks.
// readlane -> SGPR index -> SALU gather addressing; softmax shift-invariance
// (Q applied once per group). XCD-pinned swizzle (batch -> XCD pair).
// ---------------------------------------------------------------------------
__global__ __launch_bounds__(512) void pt_gr7(
    const float* __restrict__ nxyz, const unsigned* __restrict__ Sfa,
    const float* __restrict__ Wr,
    const float* __restrict__ rg, const float* __restrict__ rb,
    const float* __restrict__ rm, const float* __restrict__ rv,
    const float* __restrict__ Wx,
    const float* __restrict__ xg, const float* __restrict__ xb,
    const float* __restrict__ xm, const float* __restrict__ xv,
    const int* __restrict__ gidx, const int* __restrict__ gcnt,
    float* __restrict__ out)
{
    __shared__ __align__(16) short WT[128][72];   // refine weights [col][k]
    __shared__ __align__(16) short snf[16][72];   // softmax outputs [group][ch]

    const int tid = threadIdx.x, lane = tid & 63, w = tid >> 6;
    const int row16 = lane & 15, kg = lane >> 4;
    // bijective XCD-pinning swizzle: xcd = blk%8 serves batch (blk%8)>>1
    const int i = blockIdx.x;                     // 0..1023
    const int b = (i & 7) >> 1;
    const int j = ((i >> 3) << 1) | (i & 1);      // 0..255
    const long long gbase = (long long)b * Mc + j * 16;

    // both groups' neighbor lists in one coalesced 64-int load (wave-local)
    const int nv = gidx[(gbase + 2 * w) * 32 + lane];

    {   // WT staging: thread owns channel c = tid&127 (scale in registers)
        const int c = tid & 127, k0 = tid >> 7;
        const float sr = rg[c] * rsqrtf(rv[c] + EPSc);
#pragma unroll
        for (int it = 0; it < 16; ++it) {
            const int k = k0 + 4 * it;
            WT[c][k] = f2bf(Wr[k * 128 + c] * sr);
        }
    }

    // per-lane channel coeffs (channel = lane) + per-group constants
    const float xs = xg[lane] * rsqrtf(xv[lane] + EPSc);
    const float w0 = Wx[lane] * xs, w1 = Wx[64 + lane] * xs, w2 = Wx[128 + lane] * xs;
    const float P = xb[lane] - xm[lane] * xs;
    const float* nx = nxyz + (gbase + 2 * w) * 3;  // 6 floats = both groups
    const float QA = P - fmaf(nx[0], w0, fmaf(nx[1], w1, nx[2] * w2));
    const float QB = P - fmaf(nx[3], w0, fmaf(nx[4], w1, nx[5] * w2));

    const unsigned* sbase = Sfa + (long long)b * (Nc * 64) + lane;
    float ssA = 0.f, acA = 0.f, ssB = 0.f, acB = 0.f;
#pragma unroll
    for (int k = 0; k < Kc; ++k) {
        const int nA = __builtin_amdgcn_readlane(nv, k);        // SGPR index
        const int nB = __builtin_amdgcn_readlane(nv, 32 + k);
        const unsigned dA = sbase[nA << 6];        // SALU-addressed 256B gather
        const unsigned dB = sbase[nB << 6];
        // shift-invariance: u = exp2(hi) (Q cancels in the ratio)
        const float uA = __builtin_amdgcn_exp2f(__uint_as_float(dA & 0xffff0000u));
        const float uB = __builtin_amdgcn_exp2f(__uint_as_float(dB & 0xffff0000u));
        const float aA = __uint_as_float(dA << 16);
        const float aB = __uint_as_float(dB << 16);
        ssA += uA; acA = fmaf(uA, aA, acA);
        ssB += uB; acB = fmaf(uB, aB, acB);
    }
    snf[2 * w][lane]     = f2bf(fmaf(acA, __builtin_amdgcn_rcpf(ssA), QA));
    snf[2 * w + 1][lane] = f2bf(fmaf(acB, __builtin_amdgcn_rcpf(ssB), QB));
    __syncthreads();

    // refine MFMA: A = snf (16 rows), B = WT col-tile w
    const bf16x8 af0 = *(const bf16x8*)&snf[row16][kg * 8];
    const bf16x8 af1 = *(const bf16x8*)&snf[row16][32 + kg * 8];
    const bf16x8 bf0 = *(const bf16x8*)&WT[16 * w + row16][kg * 8];
    const bf16x8 bf1 = *(const bf16x8*)&WT[16 * w + row16][32 + kg * 8];
    f32x4 z = {0.f, 0.f, 0.f, 0.f};
    z = __builtin_amdgcn_mfma_f32_16x16x32_bf16(af0, bf0, z, 0, 0, 0);
    z = __builtin_amdgcn_mfma_f32_16x16x32_bf16(af1, bf1, z, 0, 0, 0);

    // epilogue: BN+ReLU+mask; per-lane channel cc fixed -> scale in registers
    const int4 c4 = *(const int4*)(gcnt + gbase + kg * 4);
    const int cc = 16 * w + row16;
    const float sr = rg[cc] * rsqrtf(rv[cc] + EPSc);
    const float bb = rb[cc] - rm[cc] * sr;
    float* orow = out + (gbase + kg * 4) * 128 + cc;
    __builtin_nontemporal_store(fmaxf(z[0] + bb, 0.f) * (c4.x > 0 ? 1.f : 0.f), orow);
    __builtin_nontemporal_store(fmaxf(z[1] + bb, 0.f) * (c4.y > 0 ? 1.f : 0.f), orow + 128);
    __builtin_nontemporal_store(fmaxf(z[2] + bb, 0.f) * (c4.z > 0 ? 1.f : 0.f), orow + 256);
    __builtin_nontemporal_store(fmaxf(z[3] + bb, 0.f) * (c4.w > 0 ? 1.f : 0.f), orow + 384);
}

extern "C" void kernel_launch(void* const* d_in, const int* in_sizes, int n_in,
                              void* d_out, int out_size, void* d_ws, size_t ws_size,
                              hipStream_t stream)
{
    const float* xyz  = (const float*)d_in[0];
    const float* nxyz = (const float*)d_in[1];
    const float* feats = (const float*)d_in[2];
    const float* Wf = (const float*)d_in[3];
    const float* fg = (const float*)d_in[4];
    const float* fb = (const float*)d_in[5];
    const float* fm = (const float*)d_in[6];
    const float* fv = (const float*)d_in[7];
    const float* Wa = (const float*)d_in[8];
    const float* ag = (const float*)d_in[9];
    const float* ab = (const float*)d_in[10];
    const float* am = (const float*)d_in[11];
    const float* av = (const float*)d_in[12];
    const float* Wx = (const float*)d_in[13];
    const float* xg = (const float*)d_in[14];
    const float* xb = (const float*)d_in[15];
    const float* xm = (const float*)d_in[16];
    const float* xv = (const float*)d_in[17];
    const float* Wr = (const float*)d_in[18];
    const float* rg = (const float*)d_in[19];
    const float* rb = (const float*)d_in[20];
    const float* rm = (const float*)d_in[21];
    const float* rv = (const float*)d_in[22];
    const int* gidx = (const int*)d_in[23];
    const int* gcnt = (const int*)d_in[24];
    float* out = (float*)d_out;

    unsigned* Sfa = (unsigned*)d_ws;   // B*N*64 dwords = 16 MiB packed bf16 pairs

    pt_enc<<<dim3(Bc * Nc / 64), dim3(256), 0, stream>>>(
        feats, xyz, Wf, Wa, Wx,
        fg, fb, fm, fv, ag, ab, am, av, xg, xb, xm, xv, Sfa);
    pt_gr7<<<dim3((Bc * Mc) / 16), dim3(512), 0, stream>>>(
        nxyz, Sfa, Wr, rg, rb, rm, rv, Wx, xg, xb, xm, xv,
        gidx, gcnt, out);
}

// Round 13
// 28.653 us; speedup vs baseline: 3.8829x; 1.0023x over previous
//
#include <hip/hip_runtime.h>
#include <hip/hip_bf16.h>

constexpr int Bc = 4, Nc = 16384, Mc = 4096, Kc = 32;
constexpr float EPSc = 1e-5f;
constexpr float L2E = 1.4426950408889634f;   // log2(e)

using bf16x8 = __attribute__((ext_vector_type(8))) short;   // 8 bf16 (4 VGPRs)
using f32x4  = __attribute__((ext_vector_type(4))) float;   // 4 fp32

// HW bf16 converts (v_cvt_pk_bf16_f32, RNE) — compiler pattern-matches the
// builtin casts; do NOT hand-write inline asm (m240: asm form is slower).
__device__ inline short f2bf(float x) {
    union { __hip_bfloat16 h; short s; } cv;
    cv.h = __float2bfloat16(x);
    return cv.s;
}
__device__ inline unsigned pk2(float lo, float hi) {   // low16=bf16(lo), high16=bf16(hi)
    union { __hip_bfloat162 h2; unsigned u; } cv;
    cv.h2 = __float22bfloat162_rn(make_float2(lo, hi));
    return cv.u;
}

// ---------------------------------------------------------------------------
// pt_enc (MFMA): Sfa[n][c] = pack( hi = bf16((f_bn + dot(x_n,w_c))*log2e),
//                                  lo = bf16(a_bn + dot(x_n,w_c)) )
// Batch->XCD-pair pinned swizzle identical to pt_gr7 (producer-consumer L2
// locality, R12 win). All fp32->bf16 via HW cvt_pk now.
// ---------------------------------------------------------------------------
__global__ __launch_bounds__(256) void pt_enc(
    const float* __restrict__ feats, const float* __restrict__ xyz,
    const float* __restrict__ Wf, const float* __restrict__ Wa,
    const float* __restrict__ Wx,
    const float* __restrict__ fg, const float* __restrict__ fb,
    const float* __restrict__ fm, const float* __restrict__ fv,
    const float* __restrict__ ag, const float* __restrict__ ab,
    const float* __restrict__ am, const float* __restrict__ av,
    const float* __restrict__ xg, const float* __restrict__ xb,
    const float* __restrict__ xm, const float* __restrict__ xv,
    unsigned* __restrict__ Sfa)
{
    __shared__ __align__(16) short WT[128][72];   // [col][k]
    __shared__ unsigned stile[4][16][68];         // transpose tile per wave
    __shared__ float  sx[64][3];                  // block's 64 points' xyz
    __shared__ float4 scw[64];                    // per-channel {w0,w1,w2,-}
    __shared__ float  bis[128];

    const int tid = threadIdx.x, lane = tid & 63, w = tid >> 6;
    const int row16 = lane & 15, kg = lane >> 4;
    // bijective XCD-pinning swizzle (matches pt_gr7): xcd=blk%8 -> batch (blk%8)>>1
    const int i = blockIdx.x;                     // 0..1023
    const int b = (i & 7) >> 1;
    const int j = ((i >> 3) << 1) | (i & 1);      // 0..255 tile within batch
    const long long row0 = ((long long)b * 256 + j) * 64;

    if (tid < 192) ((float*)sx)[tid] = xyz[row0 * 3 + tid];
    if (tid < 64) {
        const float xs = xg[tid] * rsqrtf(xv[tid] + EPSc);
        scw[tid] = make_float4(Wx[tid] * xs, Wx[64 + tid] * xs,
                               Wx[128 + tid] * xs, 0.f);
    }
    if (tid < 128) {
        const int c = tid & 63;
        const float g  = (tid < 64) ? fg[c] : ag[c];
        const float v  = (tid < 64) ? fv[c] : av[c];
        const float bb = (tid < 64) ? fb[c] : ab[c];
        const float mm = (tid < 64) ? fm[c] : am[c];
        const float s = g * rsqrtf(v + EPSc);
        bis[tid] = (tid < 64) ? (bb - mm * s) * L2E : (bb - mm * s);
    }
    {   // WT staging: thread owns channel c = tid&63 for both planes
        const int c = tid & 63, k0 = tid >> 6;
        const float sf = fg[c] * rsqrtf(fv[c] + EPSc) * L2E;
        const float sa = ag[c] * rsqrtf(av[c] + EPSc);
#pragma unroll
        for (int it = 0; it < 16; ++it) {
            const int k = k0 + 4 * it;
            WT[c][k]      = f2bf(Wf[k * 64 + c] * sf);
            WT[64 + c][k] = f2bf(Wa[k * 64 + c] * sa);
        }
    }
    __syncthreads();

    bf16x8 bfr[8][2];
#pragma unroll
    for (int t = 0; t < 8; ++t)
#pragma unroll
        for (int h = 0; h < 2; ++h)
            bfr[t][h] = *(const bf16x8*)&WT[16 * t + row16][32 * h + kg * 8];

    const long long base = row0 + w * 16;
    const float* arow = feats + (base + row16) * 64 + kg * 8;
    const float4 v0 = *(const float4*)(arow + 0);
    const float4 v1 = *(const float4*)(arow + 4);
    const float4 v2 = *(const float4*)(arow + 32);
    const float4 v3 = *(const float4*)(arow + 36);
    union { unsigned u[4]; bf16x8 v; } A0, A1;    // HW cvt_pk pairs
    A0.u[0] = pk2(v0.x, v0.y); A0.u[1] = pk2(v0.z, v0.w);
    A0.u[2] = pk2(v1.x, v1.y); A0.u[3] = pk2(v1.z, v1.w);
    A1.u[0] = pk2(v2.x, v2.y); A1.u[1] = pk2(v2.z, v2.w);
    A1.u[2] = pk2(v3.x, v3.y); A1.u[3] = pk2(v3.z, v3.w);

    f32x4 acc[8];
#pragma unroll
    for (int t = 0; t < 8; ++t) {
        f32x4 z = {0.f, 0.f, 0.f, 0.f};
        z = __builtin_amdgcn_mfma_f32_16x16x32_bf16(A0.v, bfr[t][0], z, 0, 0, 0);
        z = __builtin_amdgcn_mfma_f32_16x16x32_bf16(A1.v, bfr[t][1], z, 0, 0, 0);
        acc[t] = z;
    }

    // per-lane xyz-proj coeffs for this lane's 4 output cols
    float4 cwt[4];
#pragma unroll
    for (int t = 0; t < 4; ++t)
        cwt[t] = scw[16 * t + row16];

    const int lrow = w * 16 + kg * 4;
    // C/D layout: row=(lane>>4)*4+reg, col=lane&15 -> LDS tile -> coalesced
#pragma unroll
    for (int r = 0; r < 4; ++r) {
        const float x0 = sx[lrow + r][0], x1 = sx[lrow + r][1], x2 = sx[lrow + r][2];
#pragma unroll
        for (int t = 0; t < 4; ++t) {
            const int c = 16 * t + row16;
            const float px = fmaf(x0, cwt[t].x, fmaf(x1, cwt[t].y, x2 * cwt[t].z));
            // low16 = attn plane, high16 = feat plane (exp2 domain)
            stile[w][kg * 4 + r][c] = pk2(acc[t + 4][r] + bis[64 + c] + px,
                                          acc[t][r] + bis[c] + px * L2E);
        }
    }
    __syncthreads();
#pragma unroll
    for (int rr = 0; rr < 16; ++rr)
        Sfa[(base + rr) * 64 + lane] = stile[w][rr][lane];
}

// ---------------------------------------------------------------------------
// pt_gr7 (R12 structure): 512 thr = 8 waves, 2 groups/wave, 1024 blocks.
// readlane -> SGPR index -> SALU gather addressing; softmax shift-invariance
// (Q applied once per group). XCD-pinned swizzle. HW bf16 cvts in staging/snf.
// ---------------------------------------------------------------------------
__global__ __launch_bounds__(512) void pt_gr7(
    const float* __restrict__ nxyz, const unsigned* __restrict__ Sfa,
    const float* __restrict__ Wr,
    const float* __restrict__ rg, const float* __restrict__ rb,
    const float* __restrict__ rm, const float* __restrict__ rv,
    const float* __restrict__ Wx,
    const float* __restrict__ xg, const float* __restrict__ xb,
    const float* __restrict__ xm, const float* __restrict__ xv,
    const int* __restrict__ gidx, const int* __restrict__ gcnt,
    float* __restrict__ out)
{
    __shared__ __align__(16) short WT[128][72];   // refine weights [col][k]
    __shared__ __align__(16) short snf[16][72];   // softmax outputs [group][ch]

    const int tid = threadIdx.x, lane = tid & 63, w = tid >> 6;
    const int row16 = lane & 15, kg = lane >> 4;
    // bijective XCD-pinning swizzle: xcd = blk%8 serves batch (blk%8)>>1
    const int i = blockIdx.x;                     // 0..1023
    const int b = (i & 7) >> 1;
    const int j = ((i >> 3) << 1) | (i & 1);      // 0..255
    const long long gbase = (long long)b * Mc + j * 16;

    // both groups' neighbor lists in one coalesced 64-int load (wave-local)
    const int nv = gidx[(gbase + 2 * w) * 32 + lane];

    {   // WT staging: thread owns channel c = tid&127 (scale in registers)
        const int c = tid & 127, k0 = tid >> 7;
        const float sr = rg[c] * rsqrtf(rv[c] + EPSc);
#pragma unroll
        for (int it = 0; it < 16; ++it) {
            const int k = k0 + 4 * it;
            WT[c][k] = f2bf(Wr[k * 128 + c] * sr);
        }
    }

    // per-lane channel coeffs (channel = lane) + per-group constants
    const float xs = xg[lane] * rsqrtf(xv[lane] + EPSc);
    const float w0 = Wx[lane] * xs, w1 = Wx[64 + lane] * xs, w2 = Wx[128 + lane] * xs;
    const float P = xb[lane] - xm[lane] * xs;
    const float* nx = nxyz + (gbase + 2 * w) * 3;  // 6 floats = both groups
    const float QA = P - fmaf(nx[0], w0, fmaf(nx[1], w1, nx[2] * w2));
    const float QB = P - fmaf(nx[3], w0, fmaf(nx[4], w1, nx[5] * w2));

    const unsigned* sbase = Sfa + (long long)b * (Nc * 64) + lane;
    float ssA = 0.f, acA = 0.f, ssB = 0.f, acB = 0.f;
#pragma unroll
    for (int k = 0; k < Kc; ++k) {
        const int nA = __builtin_amdgcn_readlane(nv, k);        // SGPR index
        const int nB = __builtin_amdgcn_readlane(nv, 32 + k);
        const unsigned dA = sbase[nA << 6];        // SALU-addressed 256B gather
        const unsigned dB = sbase[nB << 6];
        // shift-invariance: u = exp2(hi) (Q cancels in the ratio)
        const float uA = __builtin_amdgcn_exp2f(__uint_as_float(dA & 0xffff0000u));
        const float uB = __builtin_amdgcn_exp2f(__uint_as_float(dB & 0xffff0000u));
        const float aA = __uint_as_float(dA << 16);
        const float aB = __uint_as_float(dB << 16);
        ssA += uA; acA = fmaf(uA, aA, acA);
        ssB += uB; acB = fmaf(uB, aB, acB);
    }
    snf[2 * w][lane]     = f2bf(fmaf(acA, __builtin_amdgcn_rcpf(ssA), QA));
    snf[2 * w + 1][lane] = f2bf(fmaf(acB, __builtin_amdgcn_rcpf(ssB), QB));
    __syncthreads();

    // refine MFMA: A = snf (16 rows), B = WT col-tile w
    const bf16x8 af0 = *(const bf16x8*)&snf[row16][kg * 8];
    const bf16x8 af1 = *(const bf16x8*)&snf[row16][32 + kg * 8];
    const bf16x8 bf0 = *(const bf16x8*)&WT[16 * w + row16][kg * 8];
    const bf16x8 bf1 = *(const bf16x8*)&WT[16 * w + row16][32 + kg * 8];
    f32x4 z = {0.f, 0.f, 0.f, 0.f};
    z = __builtin_amdgcn_mfma_f32_16x16x32_bf16(af0, bf0, z, 0, 0, 0);
    z = __builtin_amdgcn_mfma_f32_16x16x32_bf16(af1, bf1, z, 0, 0, 0);

    // epilogue: BN+ReLU+mask; per-lane channel cc fixed -> scale in registers
    const int4 c4 = *(const int4*)(gcnt + gbase + kg * 4);
    const int cc = 16 * w + row16;
    const float sr = rg[cc] * rsqrtf(rv[cc] + EPSc);
    const float bb = rb[cc] - rm[cc] * sr;
    float* orow = out + (gbase + kg * 4) * 128 + cc;
    __builtin_nontemporal_store(fmaxf(z[0] + bb, 0.f) * (c4.x > 0 ? 1.f : 0.f), orow);
    __builtin_nontemporal_store(fmaxf(z[1] + bb, 0.f) * (c4.y > 0 ? 1.f : 0.f), orow + 128);
    __builtin_nontemporal_store(fmaxf(z[2] + bb, 0.f) * (c4.z > 0 ? 1.f : 0.f), orow + 256);
    __builtin_nontemporal_store(fmaxf(z[3] + bb, 0.f) * (c4.w > 0 ? 1.f : 0.f), orow + 384);
}

extern "C" void kernel_launch(void* const* d_in, const int* in_sizes, int n_in,
                              void* d_out, int out_size, void* d_ws, size_t ws_size,
                              hipStream_t stream)
{
    const float* xyz  = (const float*)d_in[0];
    const float* nxyz = (const float*)d_in[1];
    const float* feats = (const float*)d_in[2];
    const float* Wf = (const float*)d_in[3];
    const float* fg = (const float*)d_in[4];
    const float* fb = (const float*)d_in[5];
    const float* fm = (const float*)d_in[6];
    const float* fv = (const float*)d_in[7];
    const float* Wa = (const float*)d_in[8];
    const float* ag = (const float*)d_in[9];
    const float* ab = (const float*)d_in[10];
    const float* am = (const float*)d_in[11];
    const float* av = (const float*)d_in[12];
    const float* Wx = (const float*)d_in[13];
    const float* xg = (const float*)d_in[14];
    const float* xb = (const float*)d_in[15];
    const float* xm = (const float*)d_in[16];
    const float* xv = (const float*)d_in[17];
    const float* Wr = (const float*)d_in[18];
    const float* rg = (const float*)d_in[19];
    const float* rb = (const float*)d_in[20];
    const float* rm = (const float*)d_in[21];
    const float* rv = (const float*)d_in[22];
    const int* gidx = (const int*)d_in[23];
    const int* gcnt = (const int*)d_in[24];
    float* out = (float*)d_out;

    unsigned* Sfa = (unsigned*)d_ws;   // B*N*64 dwords = 16 MiB packed bf16 pairs

    pt_enc<<<dim3(Bc * Nc / 64), dim3(256), 0, stream>>>(
        feats, xyz, Wf, Wa, Wx,
        fg, fb, fm, fv, ag, ab, am, av, xg, xb, xm, xv, Sfa);
    pt_gr7<<<dim3((Bc * Mc) / 16), dim3(512), 0, stream>>>(
        nxyz, Sfa, Wr, rg, rb, rm, rv, Wx, xg, xb, xm, xv,
        gidx, gcnt, out);
}